// Round 1
// baseline (1355.345 us; speedup 1.0000x reference)
//
#include <hip/hip_runtime.h>
#include <math.h>

#define ALPHA 0.1f

// ---------------- degree / normalization ----------------

__global__ void k_init_deg(float* dis, int n) {
    int i = blockIdx.x * blockDim.x + threadIdx.x;
    if (i < n) dis[i] = 1.0f;  // self-loop contributes 1 to degree
}

__global__ void k_count_deg(const int* __restrict__ col, float* dis, int e) {
    int i = blockIdx.x * blockDim.x + threadIdx.x;
    if (i < e) atomicAdd(&dis[col[i]], 1.0f);
}

__global__ void k_finish_dis(float* dis, int n) {
    int i = blockIdx.x * blockDim.x + threadIdx.x;
    if (i < n) dis[i] = rsqrtf(dis[i]);  // deg >= 1 always (self loops)
}

// ---------------- propagate, F=64 ----------------
// out[i*64+f] starts at dis[i]^2 * h[i*64+f] (self-loop term), then
// out[c*64+f] += dis[r]*dis[c] * h[r*64+f] over edges.

__global__ void k_prop_init64(const float* __restrict__ dis,
                              const float* __restrict__ h,
                              float* __restrict__ p, int n) {
    long long i = (long long)blockIdx.x * blockDim.x + threadIdx.x;
    long long total = (long long)n * 64;
    if (i >= total) return;
    int node = (int)(i >> 6);
    float d = dis[node];
    p[i] = d * d * h[i];
}

__global__ void k_prop_edges64(const int* __restrict__ row,
                               const int* __restrict__ col,
                               const float* __restrict__ dis,
                               const float* __restrict__ h,
                               float* __restrict__ p, int e) {
    long long idx = (long long)blockIdx.x * blockDim.x + threadIdx.x;
    int eid = (int)(idx >> 6);
    int f = (int)(idx & 63);
    if (eid >= e) return;
    int r = row[eid], c = col[eid];
    float w = dis[r] * dis[c];
    atomicAdd(&p[(long long)c * 64 + f], w * h[(long long)r * 64 + f]);
}

// ---------------- GCN2 layer: h = relu((0.9*p + 0.1*x0) @ W) ----------------

__global__ __launch_bounds__(256) void k_gcn2_layer(const float* __restrict__ p,
                                                    const float* __restrict__ x0,
                                                    const float* __restrict__ W,
                                                    float* __restrict__ hout, int n) {
    __shared__ float Ws[64 * 64];
    __shared__ float vs[4][64];
    int t = threadIdx.x;
    for (int i = t; i < 64 * 64; i += 256) Ws[i] = W[i];
    int ty = t >> 6, j = t & 63;
    int r = blockIdx.x * 4 + ty;
    if (r < n) {
        long long base = (long long)r * 64 + j;
        vs[ty][j] = (1.0f - ALPHA) * p[base] + ALPHA * x0[base];
    }
    __syncthreads();
    if (r >= n) return;
    float acc = 0.0f;
#pragma unroll
    for (int k = 0; k < 64; k++) acc = fmaf(vs[ty][k], Ws[k * 64 + j], acc);
    hout[(long long)r * 64 + j] = fmaxf(acc, 0.0f);
}

// ---------------- lin1: t16 = h @ w1 (64 -> 16) ----------------

__global__ __launch_bounds__(256) void k_lin1(const float* __restrict__ h,
                                              const float* __restrict__ w1,
                                              float* __restrict__ t16, int n) {
    __shared__ float Ws[64 * 16];
    int t = threadIdx.x;
    for (int i = t; i < 64 * 16; i += 256) Ws[i] = w1[i];
    __syncthreads();
    long long idx = (long long)blockIdx.x * 256 + t;
    int r = (int)(idx >> 4), j = (int)(idx & 15);
    if (r >= n) return;
    float acc = 0.0f;
#pragma unroll
    for (int k = 0; k < 64; k++) acc = fmaf(h[(long long)r * 64 + k], Ws[k * 16 + j], acc);
    t16[(long long)r * 16 + j] = acc;
}

// ---------------- propagate, F=16 ----------------

__global__ void k_prop_init16(const float* __restrict__ dis,
                              const float* __restrict__ t16,
                              float* __restrict__ p16, int n) {
    long long i = (long long)blockIdx.x * blockDim.x + threadIdx.x;
    long long total = (long long)n * 16;
    if (i >= total) return;
    int node = (int)(i >> 4);
    float d = dis[node];
    p16[i] = d * d * t16[i];
}

__global__ void k_prop_edges16(const int* __restrict__ row,
                               const int* __restrict__ col,
                               const float* __restrict__ dis,
                               const float* __restrict__ t16,
                               float* __restrict__ p16, int e) {
    long long idx = (long long)blockIdx.x * blockDim.x + threadIdx.x;
    int eid = (int)(idx >> 4);
    int f = (int)(idx & 15);
    if (eid >= e) return;
    int r = row[eid], c = col[eid];
    float w = dis[r] * dis[c];
    atomicAdd(&p16[(long long)c * 16 + f], w * t16[(long long)r * 16 + f]);
}

// ---------------- lin2: t1 = (p16 + b1) @ w2 (16 -> 1) ----------------

__global__ void k_lin2(const float* __restrict__ p16,
                       const float* __restrict__ b1,
                       const float* __restrict__ w2,
                       float* __restrict__ t1, int n) {
    int i = blockIdx.x * blockDim.x + threadIdx.x;
    if (i >= n) return;
    float acc = 0.0f;
#pragma unroll
    for (int j = 0; j < 16; j++) acc = fmaf(p16[(long long)i * 16 + j] + b1[j], w2[j], acc);
    t1[i] = acc;
}

// ---------------- propagate, F=1, into d_out ----------------

__global__ void k_prop_init1(const float* __restrict__ dis,
                             const float* __restrict__ t1,
                             float* __restrict__ out, int n) {
    int i = blockIdx.x * blockDim.x + threadIdx.x;
    if (i >= n) return;
    float d = dis[i];
    out[i] = d * d * t1[i];
}

__global__ void k_prop_edges1(const int* __restrict__ row,
                              const int* __restrict__ col,
                              const float* __restrict__ dis,
                              const float* __restrict__ t1,
                              float* __restrict__ out, int e) {
    int i = blockIdx.x * blockDim.x + threadIdx.x;
    if (i >= e) return;
    int r = row[i], c = col[i];
    atomicAdd(&out[c], dis[r] * dis[c] * t1[r]);
}

__global__ void k_sigmoid(float* __restrict__ out, const float* __restrict__ b2, int n) {
    int i = blockIdx.x * blockDim.x + threadIdx.x;
    if (i >= n) return;
    float v = out[i] + b2[0];
    out[i] = 1.0f / (1.0f + expf(-v));
}

// ---------------- launch ----------------

extern "C" void kernel_launch(void* const* d_in, const int* in_sizes, int n_in,
                              void* d_out, int out_size, void* d_ws, size_t ws_size,
                              hipStream_t stream) {
    const float* x  = (const float*)d_in[0];
    const int*   ei = (const int*)d_in[1];
    const float* gw = (const float*)d_in[2];
    const float* w1 = (const float*)d_in[3];
    const float* b1 = (const float*)d_in[4];
    const float* w2 = (const float*)d_in[5];
    const float* b2 = (const float*)d_in[6];
    float* out = (float*)d_out;

    const int N = in_sizes[0] / 64;
    const int E = in_sizes[1] / 2;
    const int L = in_sizes[2] / (64 * 64);

    const int* row = ei;
    const int* col = ei + E;

    float* ws  = (float*)d_ws;
    float* dis = ws;                       // N
    float* h   = dis + N;                  // N*64
    float* p   = h + (long long)N * 64;    // N*64
    float* t16 = p;                        // N*16 (reuse p after last GCN2 layer)
    float* p16 = p + (long long)N * 16;    // N*16
    float* t1  = h;                        // N (reuse h)

    const int B = 256;
    int gN   = (N + B - 1) / B;
    int gE   = (E + B - 1) / B;
    int gN64 = (int)(((long long)N * 64 + B - 1) / B);
    int gE64 = (int)(((long long)E * 64 + B - 1) / B);
    int gN16 = (int)(((long long)N * 16 + B - 1) / B);
    int gE16 = (int)(((long long)E * 16 + B - 1) / B);

    // normalization
    k_init_deg<<<gN, B, 0, stream>>>(dis, N);
    k_count_deg<<<gE, B, 0, stream>>>(col, dis, E);
    k_finish_dis<<<gN, B, 0, stream>>>(dis, N);

    // GCN2 stack
    const float* hin = x;
    for (int l = 0; l < L; l++) {
        k_prop_init64<<<gN64, B, 0, stream>>>(dis, hin, p, N);
        k_prop_edges64<<<gE64, B, 0, stream>>>(row, col, dis, hin, p, E);
        k_gcn2_layer<<<(N + 3) / 4, B, 0, stream>>>(p, x, gw + (long long)l * 64 * 64, h, N);
        hin = h;
    }

    // GCNConv(64->16)
    k_lin1<<<(int)(((long long)N * 16 + B - 1) / B), B, 0, stream>>>(h, w1, t16, N);
    k_prop_init16<<<gN16, B, 0, stream>>>(dis, t16, p16, N);
    k_prop_edges16<<<gE16, B, 0, stream>>>(row, col, dis, t16, p16, E);

    // GCNConv(16->1)
    k_lin2<<<gN, B, 0, stream>>>(p16, b1, w2, t1, N);
    k_prop_init1<<<gN, B, 0, stream>>>(dis, t1, out, N);
    k_prop_edges1<<<gE, B, 0, stream>>>(row, col, dis, t1, out, E);
    k_sigmoid<<<gN, B, 0, stream>>>(out, b2, N);
}

// Round 2
// 840.699 us; speedup vs baseline: 1.6122x; 1.6122x over previous
//
#include <hip/hip_runtime.h>
#include <math.h>

#define ALPHA 0.1f

// ================= CSR build =================

__global__ void k_zero(int* cnt, int n) {
    int i = blockIdx.x * blockDim.x + threadIdx.x;
    if (i < n) cnt[i] = 0;
}

__global__ void k_count(const int* __restrict__ col, int* cnt, int e) {
    int i = blockIdx.x * blockDim.x + threadIdx.x;
    if (i < e) atomicAdd(&cnt[col[i]], 1);
}

__global__ void k_dis(const int* __restrict__ cnt, float* dis, int n) {
    int i = blockIdx.x * blockDim.x + threadIdx.x;
    if (i < n) dis[i] = rsqrtf((float)cnt[i] + 1.0f);  // +1 self-loop
}

// block-level exclusive scan, 256 elems/block
__global__ __launch_bounds__(256) void k_scan_block(const int* __restrict__ cnt,
                                                    int* __restrict__ off,
                                                    int* __restrict__ bsum, int n) {
    __shared__ int s[256];
    int t = threadIdx.x;
    int i = blockIdx.x * 256 + t;
    int v = (i < n) ? cnt[i] : 0;
    s[t] = v;
    __syncthreads();
    for (int d = 1; d < 256; d <<= 1) {
        int add = (t >= d) ? s[t - d] : 0;
        __syncthreads();
        s[t] += add;
        __syncthreads();
    }
    if (i < n) off[i] = s[t] - v;  // exclusive
    if (t == 255) bsum[blockIdx.x] = s[255];
}

// scan the block sums (nb <= 512 for N=100k; 391 blocks)
__global__ __launch_bounds__(512) void k_scan_bsum(int* __restrict__ bsum, int nb) {
    __shared__ int s[512];
    int t = threadIdx.x;
    int v = (t < nb) ? bsum[t] : 0;
    s[t] = v;
    __syncthreads();
    for (int d = 1; d < 512; d <<= 1) {
        int add = (t >= d) ? s[t - d] : 0;
        __syncthreads();
        s[t] += add;
        __syncthreads();
    }
    if (t < nb) bsum[t] = s[t] - v;  // exclusive
}

__global__ void k_scan_add(int* __restrict__ off, const int* __restrict__ bsum, int n) {
    int i = blockIdx.x * 256 + threadIdx.x;
    if (i < n) off[i] += bsum[blockIdx.x];
}

// scatter rows into CSR order; mutates off[c] from start -> end cursor.
// After this kernel: off[c] == end of segment c (== start of segment c+1).
__global__ void k_scatter(const int* __restrict__ row, const int* __restrict__ col,
                          int* __restrict__ off, int* __restrict__ srow, int e) {
    int i = blockIdx.x * blockDim.x + threadIdx.x;
    if (i >= e) return;
    int pos = atomicAdd(&off[col[i]], 1);
    srow[pos] = row[i];
}

// ================= fused GCN2 layer =================
// One wave per node c, lane = feature f.
// p = dis[c] * ( sum_e dis[r]*hin[r][f]  +  dis[c]*hin[c][f] )
// v = 0.9*p + 0.1*x0 ;  hout = relu(v @ W)

__global__ __launch_bounds__(256) void k_gcn2_fused(const int* __restrict__ srow,
                                                    const int* __restrict__ endoff,
                                                    const float* __restrict__ dis,
                                                    const float* __restrict__ hin,
                                                    const float* __restrict__ x0,
                                                    const float* __restrict__ W,
                                                    float* __restrict__ hout, int n) {
    __shared__ float Ws[64 * 64];
    __shared__ float vs[4][64];
    int t = threadIdx.x;
    for (int i = t; i < 64 * 64; i += 256) Ws[i] = W[i];
    int w = t >> 6, f = t & 63;
    int c = blockIdx.x * 4 + w;
    float v = 0.0f;
    if (c < n) {
        int start = (c == 0) ? 0 : endoff[c - 1];
        int end = endoff[c];
        float dc = dis[c];
        float s = 0.0f;
        for (int e = start; e < end; e++) {
            int r = srow[e];
            s += dis[r] * hin[(long long)r * 64 + f];
        }
        float p = dc * (s + dc * hin[(long long)c * 64 + f]);
        v = (1.0f - ALPHA) * p + ALPHA * x0[(long long)c * 64 + f];
    }
    vs[w][f] = v;
    __syncthreads();
    if (c >= n) return;
    float acc = 0.0f;
#pragma unroll
    for (int k = 0; k < 64; k++) acc = fmaf(vs[w][k], Ws[k * 64 + f], acc);
    hout[(long long)c * 64 + f] = fmaxf(acc, 0.0f);
}

// ================= GCNConv(64->16) =================

__global__ __launch_bounds__(256) void k_lin1(const float* __restrict__ h,
                                              const float* __restrict__ w1,
                                              float* __restrict__ t16, int n) {
    __shared__ float Ws[64 * 16];
    int t = threadIdx.x;
    for (int i = t; i < 64 * 16; i += 256) Ws[i] = w1[i];
    __syncthreads();
    long long idx = (long long)blockIdx.x * 256 + t;
    int r = (int)(idx >> 4), j = (int)(idx & 15);
    if (r >= n) return;
    float acc = 0.0f;
#pragma unroll
    for (int k = 0; k < 64; k++) acc = fmaf(h[(long long)r * 64 + k], Ws[k * 16 + j], acc);
    t16[(long long)r * 16 + j] = acc;
}

// gather propagate F=16 (thread per (node, feature))
__global__ void k_prop16_csr(const int* __restrict__ srow, const int* __restrict__ endoff,
                             const float* __restrict__ dis, const float* __restrict__ t16,
                             float* __restrict__ p16, int n) {
    long long idx = (long long)blockIdx.x * 256 + threadIdx.x;
    int c = (int)(idx >> 4), f = (int)(idx & 15);
    if (c >= n) return;
    int start = (c == 0) ? 0 : endoff[c - 1];
    int end = endoff[c];
    float dc = dis[c];
    float s = 0.0f;
    for (int e = start; e < end; e++) {
        int r = srow[e];
        s += dis[r] * t16[(long long)r * 16 + f];
    }
    p16[idx] = dc * (s + dc * t16[(long long)c * 16 + f]);
}

// ================= GCNConv(16->1) =================

__global__ void k_lin2(const float* __restrict__ p16, const float* __restrict__ b1,
                       const float* __restrict__ w2, float* __restrict__ t1, int n) {
    int i = blockIdx.x * blockDim.x + threadIdx.x;
    if (i >= n) return;
    float acc = 0.0f;
#pragma unroll
    for (int j = 0; j < 16; j++) acc = fmaf(p16[(long long)i * 16 + j] + b1[j], w2[j], acc);
    t1[i] = acc;
}

// gather propagate F=1 + b2 + sigmoid, straight into d_out
__global__ void k_prop1_csr(const int* __restrict__ srow, const int* __restrict__ endoff,
                            const float* __restrict__ dis, const float* __restrict__ t1,
                            const float* __restrict__ b2, float* __restrict__ out, int n) {
    int c = blockIdx.x * blockDim.x + threadIdx.x;
    if (c >= n) return;
    int start = (c == 0) ? 0 : endoff[c - 1];
    int end = endoff[c];
    float dc = dis[c];
    float s = 0.0f;
    for (int e = start; e < end; e++) {
        int r = srow[e];
        s += dis[r] * t1[r];
    }
    float v = dc * (s + dc * t1[c]) + b2[0];
    out[c] = 1.0f / (1.0f + expf(-v));
}

// ================= launch =================

extern "C" void kernel_launch(void* const* d_in, const int* in_sizes, int n_in,
                              void* d_out, int out_size, void* d_ws, size_t ws_size,
                              hipStream_t stream) {
    const float* x  = (const float*)d_in[0];
    const int*   ei = (const int*)d_in[1];
    const float* gw = (const float*)d_in[2];
    const float* w1 = (const float*)d_in[3];
    const float* b1 = (const float*)d_in[4];
    const float* w2 = (const float*)d_in[5];
    const float* b2 = (const float*)d_in[6];
    float* out = (float*)d_out;

    const int N = in_sizes[0] / 64;
    const int E = in_sizes[1] / 2;
    const int L = in_sizes[2] / (64 * 64);

    const int* row = ei;
    const int* col = ei + E;

    // workspace layout
    char* wsb = (char*)d_ws;
    int*   cnt  = (int*)wsb;                          // N
    float* dis  = (float*)(cnt + N);                  // N
    int*   off  = (int*)(dis + N);                    // N (becomes end-offsets)
    int*   bsum = off + N;                            // 1024
    int*   srow = bsum + 1024;                        // E
    float* h0   = (float*)(srow + E);                 // N*64
    float* h1   = h0 + (long long)N * 64;             // N*64
    float* t16  = h0;                                 // reuse (final h is h1 for even L)
    float* p16  = h0 + (long long)N * 16;
    float* t1   = h0 + (long long)N * 32;

    const int B = 256;
    int gN = (N + B - 1) / B;
    int gE = (E + B - 1) / B;
    int nb = (N + 255) / 256;  // scan blocks (must be <= 512; 391 for N=100k)

    // CSR build + normalization
    k_zero<<<gN, B, 0, stream>>>(cnt, N);
    k_count<<<gE, B, 0, stream>>>(col, cnt, E);
    k_dis<<<gN, B, 0, stream>>>(cnt, dis, N);
    k_scan_block<<<nb, 256, 0, stream>>>(cnt, off, bsum, N);
    k_scan_bsum<<<1, 512, 0, stream>>>(bsum, nb);
    k_scan_add<<<nb, 256, 0, stream>>>(off, bsum, N);
    k_scatter<<<gE, B, 0, stream>>>(row, col, off, srow, E);
    // off[c] now holds end of segment c

    // GCN2 stack (fused propagate + combine + GEMM + relu)
    const float* hin = x;
    float* bufs[2] = {h0, h1};
    for (int l = 0; l < L; l++) {
        float* hout = bufs[l & 1];
        k_gcn2_fused<<<(N + 3) / 4, B, 0, stream>>>(srow, off, dis, hin, x,
                                                    gw + (long long)l * 64 * 64, hout, N);
        hin = hout;
    }
    // for L=4 final is h1; t16/p16/t1 live in h0 region (safe)

    // GCNConv(64->16)
    k_lin1<<<(int)(((long long)N * 16 + B - 1) / B), B, 0, stream>>>(hin, w1, t16, N);
    k_prop16_csr<<<(int)(((long long)N * 16 + B - 1) / B), B, 0, stream>>>(srow, off, dis, t16, p16, N);

    // GCNConv(16->1) + sigmoid
    k_lin2<<<gN, B, 0, stream>>>(p16, b1, w2, t1, N);
    k_prop1_csr<<<gN, B, 0, stream>>>(srow, off, dis, t1, b2, out, N);
}

// Round 3
// 610.374 us; speedup vs baseline: 2.2205x; 1.3774x over previous
//
#include <hip/hip_runtime.h>
#include <hip/hip_fp16.h>
#include <math.h>

#define ALPHA 0.1f

// ================= CSR build =================

__global__ void k_zero(int* cnt, int n) {
    int i = blockIdx.x * blockDim.x + threadIdx.x;
    if (i < n) cnt[i] = 0;
}

__global__ void k_count(const int* __restrict__ col, int* cnt, int e) {
    int i = blockIdx.x * blockDim.x + threadIdx.x;
    if (i < e) atomicAdd(&cnt[col[i]], 1);
}

__global__ void k_dis(const int* __restrict__ cnt, float* dis, int n) {
    int i = blockIdx.x * blockDim.x + threadIdx.x;
    if (i < n) dis[i] = rsqrtf((float)cnt[i] + 1.0f);  // +1 self-loop
}

__global__ __launch_bounds__(256) void k_scan_block(const int* __restrict__ cnt,
                                                    int* __restrict__ off,
                                                    int* __restrict__ bsum, int n) {
    __shared__ int s[256];
    int t = threadIdx.x;
    int i = blockIdx.x * 256 + t;
    int v = (i < n) ? cnt[i] : 0;
    s[t] = v;
    __syncthreads();
    for (int d = 1; d < 256; d <<= 1) {
        int add = (t >= d) ? s[t - d] : 0;
        __syncthreads();
        s[t] += add;
        __syncthreads();
    }
    if (i < n) off[i] = s[t] - v;
    if (t == 255) bsum[blockIdx.x] = s[255];
}

__global__ __launch_bounds__(512) void k_scan_bsum(int* __restrict__ bsum, int nb) {
    __shared__ int s[512];
    int t = threadIdx.x;
    int v = (t < nb) ? bsum[t] : 0;
    s[t] = v;
    __syncthreads();
    for (int d = 1; d < 512; d <<= 1) {
        int add = (t >= d) ? s[t - d] : 0;
        __syncthreads();
        s[t] += add;
        __syncthreads();
    }
    if (t < nb) bsum[t] = s[t] - v;
}

__global__ void k_scan_add(int* __restrict__ off, const int* __restrict__ bsum, int n) {
    int i = blockIdx.x * 256 + threadIdx.x;
    if (i < n) off[i] += bsum[blockIdx.x];
}

// After this kernel off[c] == end of segment c.
__global__ void k_scatter(const int* __restrict__ row, const int* __restrict__ col,
                          int* __restrict__ off, int* __restrict__ srow, int e) {
    int i = blockIdx.x * blockDim.x + threadIdx.x;
    if (i >= e) return;
    int pos = atomicAdd(&off[col[i]], 1);
    srow[pos] = row[i];
}

// ================= prescale x into fp16 =================
// xs[i][f] = dis[i] * x[i][f]

__global__ void k_prescale(const float* __restrict__ x, const float* __restrict__ dis,
                           __half* __restrict__ xs, long long total) {
    long long i = (long long)blockIdx.x * blockDim.x + threadIdx.x;
    if (i >= total) return;
    xs[i] = __float2half(dis[i >> 6] * x[i]);
}

// ================= fused GCN2 layer =================
// hs_in[r] = dis[r]*h[r] (fp16). Per node c (one wave):
//   tot[f] = sum_{e in seg(c)} hs_in[srow[e]][f] + hs_in[c][f]
//   v = 0.9*dis[c]*tot + 0.1*x0[c]
//   h = relu(v @ W);  hs_out[c] = fp16(dis[c]*h)
// Gather: 8 edge slots/wave, 8 fp16 (16B) per lane, butterfly xor 8/16/32.

__global__ __launch_bounds__(256) void k_gcn2_fused(
    const int* __restrict__ srow, const int* __restrict__ endoff,
    const float* __restrict__ dis, const __half* __restrict__ hs_in,
    const float* __restrict__ x0, const float* __restrict__ W,
    __half* __restrict__ hs_out, int n)
{
    __shared__ float Ws[64 * 64];
    __shared__ float vs[4][64];
    int t = threadIdx.x;
    for (int i = t; i < 64 * 64; i += 256) Ws[i] = W[i];

    int w = t >> 6;        // wave id = node slot in block
    int lane = t & 63;
    int g = lane >> 3;     // edge slot 0..7
    int s = lane & 7;      // feature octet 0..7
    int c = blockIdx.x * 4 + w;

    if (c < n) {
        int start = (c == 0) ? 0 : endoff[c - 1];
        int end = endoff[c];
        float a0=0,a1=0,a2=0,a3=0,a4=0,a5=0,a6=0,a7=0;
        if (g == 0) {  // self-loop term (hs_in[c] already dis[c]-scaled)
            float4 q = *(const float4*)(hs_in + (size_t)c * 64 + s * 8);
            float2 u;
            u = __half22float2(*(__half2*)&q.x); a0 = u.x; a1 = u.y;
            u = __half22float2(*(__half2*)&q.y); a2 = u.x; a3 = u.y;
            u = __half22float2(*(__half2*)&q.z); a4 = u.x; a5 = u.y;
            u = __half22float2(*(__half2*)&q.w); a6 = u.x; a7 = u.y;
        }
        for (int e = start + g; e < end; e += 8) {
            int r = srow[e];
            float4 q = *(const float4*)(hs_in + (size_t)r * 64 + s * 8);
            float2 u;
            u = __half22float2(*(__half2*)&q.x); a0 += u.x; a1 += u.y;
            u = __half22float2(*(__half2*)&q.y); a2 += u.x; a3 += u.y;
            u = __half22float2(*(__half2*)&q.z); a4 += u.x; a5 += u.y;
            u = __half22float2(*(__half2*)&q.w); a6 += u.x; a7 += u.y;
        }
#pragma unroll
        for (int d = 8; d <= 32; d <<= 1) {
            a0 += __shfl_xor(a0, d, 64); a1 += __shfl_xor(a1, d, 64);
            a2 += __shfl_xor(a2, d, 64); a3 += __shfl_xor(a3, d, 64);
            a4 += __shfl_xor(a4, d, 64); a5 += __shfl_xor(a5, d, 64);
            a6 += __shfl_xor(a6, d, 64); a7 += __shfl_xor(a7, d, 64);
        }
        if (g == 0) {
            float dc = dis[c];
            const float* xp = x0 + (size_t)c * 64 + s * 8;
            float v0 = (1.0f - ALPHA) * (dc * a0) + ALPHA * xp[0];
            float v1 = (1.0f - ALPHA) * (dc * a1) + ALPHA * xp[1];
            float v2 = (1.0f - ALPHA) * (dc * a2) + ALPHA * xp[2];
            float v3 = (1.0f - ALPHA) * (dc * a3) + ALPHA * xp[3];
            float v4 = (1.0f - ALPHA) * (dc * a4) + ALPHA * xp[4];
            float v5 = (1.0f - ALPHA) * (dc * a5) + ALPHA * xp[5];
            float v6 = (1.0f - ALPHA) * (dc * a6) + ALPHA * xp[6];
            float v7 = (1.0f - ALPHA) * (dc * a7) + ALPHA * xp[7];
            float* vp = &vs[w][s * 8];
            vp[0]=v0; vp[1]=v1; vp[2]=v2; vp[3]=v3;
            vp[4]=v4; vp[5]=v5; vp[6]=v6; vp[7]=v7;
        }
    }
    __syncthreads();
    if (c >= n) return;
    int f = lane;
    float acc = 0.0f;
#pragma unroll
    for (int k = 0; k < 64; k++) acc = fmaf(vs[w][k], Ws[k * 64 + f], acc);
    float h = fmaxf(acc, 0.0f);
    hs_out[(size_t)c * 64 + f] = __float2half(dis[c] * h);
}

// ================= lin1: t16s = hs @ w1  (dis prescale cancels) =================

__global__ __launch_bounds__(256) void k_lin1(const __half* __restrict__ hs,
                                              const float* __restrict__ w1,
                                              __half* __restrict__ t16s, int n) {
    __shared__ float Ws[64 * 16];
    int t = threadIdx.x;
    for (int i = t; i < 64 * 16; i += 256) Ws[i] = w1[i];
    __syncthreads();
    long long idx = (long long)blockIdx.x * 256 + t;
    int r = (int)(idx >> 4), j = (int)(idx & 15);
    if (r >= n) return;
    const __half* hp = hs + (size_t)r * 64;
    float acc = 0.0f;
#pragma unroll
    for (int k = 0; k < 64; k += 2) {
        float2 u = __half22float2(*(const __half2*)(hp + k));
        acc = fmaf(u.x, Ws[k * 16 + j], acc);
        acc = fmaf(u.y, Ws[(k + 1) * 16 + j], acc);
    }
    t16s[idx] = __float2half(acc);
}

// ================= fused prop16 + lin2 =================
// p16 = dc*(sum_e t16s[r] + t16s[c]);  t1s[c] = dc*((p16+b1)@w2)
// 16 edge slots/wave, 4 fp16 (8B) per lane.

__global__ __launch_bounds__(256) void k_prop16_lin2(
    const int* __restrict__ srow, const int* __restrict__ endoff,
    const float* __restrict__ dis, const __half* __restrict__ t16s,
    const float* __restrict__ b1, const float* __restrict__ w2,
    float* __restrict__ t1s, int n)
{
    int t = threadIdx.x;
    int w = t >> 6, lane = t & 63;
    int g = lane >> 2;   // edge slot 0..15
    int s = lane & 3;    // feature quad 0..3
    int c = blockIdx.x * 4 + w;
    if (c >= n) return;
    int start = (c == 0) ? 0 : endoff[c - 1];
    int end = endoff[c];
    float a0=0,a1=0,a2=0,a3=0;
    if (g == 0) {
        float2 q = *(const float2*)(t16s + (size_t)c * 16 + s * 4);
        float2 u;
        u = __half22float2(*(__half2*)&q.x); a0 = u.x; a1 = u.y;
        u = __half22float2(*(__half2*)&q.y); a2 = u.x; a3 = u.y;
    }
    for (int e = start + g; e < end; e += 16) {
        int r = srow[e];
        float2 q = *(const float2*)(t16s + (size_t)r * 16 + s * 4);
        float2 u;
        u = __half22float2(*(__half2*)&q.x); a0 += u.x; a1 += u.y;
        u = __half22float2(*(__half2*)&q.y); a2 += u.x; a3 += u.y;
    }
#pragma unroll
    for (int d = 4; d <= 32; d <<= 1) {
        a0 += __shfl_xor(a0, d, 64); a1 += __shfl_xor(a1, d, 64);
        a2 += __shfl_xor(a2, d, 64); a3 += __shfl_xor(a3, d, 64);
    }
    float dc = dis[c];
    float4 b = *(const float4*)(b1 + s * 4);
    float4 ww = *(const float4*)(w2 + s * 4);
    float partial = (dc * a0 + b.x) * ww.x + (dc * a1 + b.y) * ww.y +
                    (dc * a2 + b.z) * ww.z + (dc * a3 + b.w) * ww.w;
    partial += __shfl_xor(partial, 1, 64);
    partial += __shfl_xor(partial, 2, 64);
    if (lane == 0) t1s[c] = dc * partial;
}

// ================= prop1 + sigmoid =================

__global__ void k_prop1(const int* __restrict__ srow, const int* __restrict__ endoff,
                        const float* __restrict__ dis, const float* __restrict__ t1s,
                        const float* __restrict__ b2, float* __restrict__ out, int n) {
    int c = blockIdx.x * blockDim.x + threadIdx.x;
    if (c >= n) return;
    int start = (c == 0) ? 0 : endoff[c - 1];
    int end = endoff[c];
    float ssum = t1s[c];
    for (int e = start; e < end; e++) ssum += t1s[srow[e]];
    float v = dis[c] * ssum + b2[0];
    out[c] = 1.0f / (1.0f + expf(-v));
}

// ================= launch =================

static inline char* align16(char* p) {
    return (char*)(((uintptr_t)p + 15) & ~(uintptr_t)15);
}

extern "C" void kernel_launch(void* const* d_in, const int* in_sizes, int n_in,
                              void* d_out, int out_size, void* d_ws, size_t ws_size,
                              hipStream_t stream) {
    const float* x  = (const float*)d_in[0];
    const int*   ei = (const int*)d_in[1];
    const float* gw = (const float*)d_in[2];
    const float* w1 = (const float*)d_in[3];
    const float* b1 = (const float*)d_in[4];
    const float* w2 = (const float*)d_in[5];
    const float* b2 = (const float*)d_in[6];
    float* out = (float*)d_out;

    const int N = in_sizes[0] / 64;
    const int E = in_sizes[1] / 2;
    const int L = in_sizes[2] / (64 * 64);

    const int* row = ei;
    const int* col = ei + E;

    char* p = (char*)d_ws;
    int* cnt = (int*)p;            p = align16(p + (size_t)N * 4);
    int* off = (int*)p;            p = align16(p + (size_t)N * 4);
    int* bsum = (int*)p;           p = align16(p + 4096);
    float* dis = (float*)p;        p = align16(p + (size_t)N * 4);
    int* srow = (int*)p;           p = align16(p + (size_t)E * 4);
    __half* hsA = (__half*)p;      p = align16(p + (size_t)N * 128);
    __half* hsB = (__half*)p;      p = align16(p + (size_t)N * 128);
    __half* t16s = (__half*)p;     p = align16(p + (size_t)N * 32);
    float* t1s = (float*)p;

    const int B = 256;
    int gN = (N + B - 1) / B;
    int gE = (E + B - 1) / B;
    int nb = (N + 255) / 256;

    // CSR + normalization
    k_zero<<<gN, B, 0, stream>>>(cnt, N);
    k_count<<<gE, B, 0, stream>>>(col, cnt, E);
    k_dis<<<gN, B, 0, stream>>>(cnt, dis, N);
    k_scan_block<<<nb, 256, 0, stream>>>(cnt, off, bsum, N);
    k_scan_bsum<<<1, 512, 0, stream>>>(bsum, nb);
    k_scan_add<<<nb, 256, 0, stream>>>(off, bsum, N);
    k_scatter<<<gE, B, 0, stream>>>(row, col, off, srow, E);

    // prescale x -> hsA (fp16, dis-scaled)
    long long tot64 = (long long)N * 64;
    k_prescale<<<(int)((tot64 + B - 1) / B), B, 0, stream>>>(x, dis, hsA, tot64);

    // GCN2 stack
    __half* bufs[2] = {hsA, hsB};
    const __half* hin = hsA;
    for (int l = 0; l < L; l++) {
        __half* hout = bufs[(l + 1) & 1];  // l=0: ->hsB, l=1: ->hsA, ...
        k_gcn2_fused<<<(N + 3) / 4, B, 0, stream>>>(srow, off, dis, hin, x,
                                                    gw + (long long)l * 64 * 64, hout, N);
        hin = hout;
    }

    // GCNConv(64->16): t16s = hs @ w1 (prescale cancels)
    k_lin1<<<(int)(((long long)N * 16 + B - 1) / B), B, 0, stream>>>(hin, w1, t16s, N);
    // fused propagate16 + lin2
    k_prop16_lin2<<<(N + 3) / 4, B, 0, stream>>>(srow, off, dis, t16s, b1, w2, t1s, N);
    // propagate1 + bias + sigmoid
    k_prop1<<<gN, B, 0, stream>>>(srow, off, dis, t1s, b2, out, N);
}

// Round 4
// 381.862 us; speedup vs baseline: 3.5493x; 1.5984x over previous
//
#include <hip/hip_runtime.h>
#include <hip/hip_fp16.h>
#include <math.h>

#define ALPHA 0.1f

typedef _Float16 f16x8 __attribute__((ext_vector_type(8)));
typedef float f32x4 __attribute__((ext_vector_type(4)));

// ================= CSR build =================

__global__ void k_zero(int* cnt, int n) {
    int i = blockIdx.x * blockDim.x + threadIdx.x;
    if (i < n) cnt[i] = 0;
}

__global__ void k_count(const int* __restrict__ col, int* cnt, int e) {
    int i = blockIdx.x * blockDim.x + threadIdx.x;
    if (i < e) atomicAdd(&cnt[col[i]], 1);
}

__global__ void k_dis(const int* __restrict__ cnt, float* dis, int n) {
    int i = blockIdx.x * blockDim.x + threadIdx.x;
    if (i < n) dis[i] = rsqrtf((float)cnt[i] + 1.0f);  // +1 self-loop
}

__global__ __launch_bounds__(256) void k_scan_block(const int* __restrict__ cnt,
                                                    int* __restrict__ off,
                                                    int* __restrict__ bsum, int n) {
    __shared__ int s[256];
    int t = threadIdx.x;
    int i = blockIdx.x * 256 + t;
    int v = (i < n) ? cnt[i] : 0;
    s[t] = v;
    __syncthreads();
    for (int d = 1; d < 256; d <<= 1) {
        int add = (t >= d) ? s[t - d] : 0;
        __syncthreads();
        s[t] += add;
        __syncthreads();
    }
    if (i < n) off[i] = s[t] - v;
    if (t == 255) bsum[blockIdx.x] = s[255];
}

__global__ __launch_bounds__(512) void k_scan_bsum(int* __restrict__ bsum, int nb) {
    __shared__ int s[512];
    int t = threadIdx.x;
    int v = (t < nb) ? bsum[t] : 0;
    s[t] = v;
    __syncthreads();
    for (int d = 1; d < 512; d <<= 1) {
        int add = (t >= d) ? s[t - d] : 0;
        __syncthreads();
        s[t] += add;
        __syncthreads();
    }
    if (t < nb) bsum[t] = s[t] - v;
}

__global__ void k_scan_add(int* __restrict__ off, const int* __restrict__ bsum, int n) {
    int i = blockIdx.x * 256 + threadIdx.x;
    if (i < n) off[i] += bsum[blockIdx.x];
}

// After this kernel off[c] == end of segment c.
__global__ void k_scatter(const int* __restrict__ row, const int* __restrict__ col,
                          int* __restrict__ off, int* __restrict__ srow, int e) {
    int i = blockIdx.x * blockDim.x + threadIdx.x;
    if (i >= e) return;
    int pos = atomicAdd(&off[col[i]], 1);
    srow[pos] = row[i];
}

// ================= prescale =================
// xs[i] = fp16(dis * x)   (the propagated feature carrier)
// x0h[i] = fp16(ALPHA * x)  (pre-scaled residual)

__global__ void k_prescale(const float* __restrict__ x, const float* __restrict__ dis,
                           __half* __restrict__ xs, __half* __restrict__ x0h,
                           long long total) {
    long long i = (long long)blockIdx.x * blockDim.x + threadIdx.x;
    if (i >= total) return;
    float xv = x[i];
    float d = dis[i >> 6];
    xs[i] = __float2half(d * xv);
    x0h[i] = __float2half(ALPHA * xv);
}

// ================= fused GCN2 layer (MFMA) =================
// Block: 256 threads (4 waves) -> 32 nodes.
// Gather: lane = (j node 0..7, s octet 0..7); wave w covers nodes w*8..w*8+7.
//   tot[f] = sum_e hs_in[srow[e]][f] + hs_in[c][f]   (hs_in pre-scaled by dis)
//   v = 0.9*dis[c]*tot + x0h[c]  -> fp16 in LDS vs[32][72]
// GEMM: W^T in LDS fp16 (WsT[n][k], pad 72); wave w computes cols 16w..16w+15
//   via mfma_f32_16x16x32_f16, two M-tiles of 16 nodes.
// Epilogue: relu, rescale by dis[c], store fp16.

__global__ __launch_bounds__(256) void k_gcn2_fused(
    const int* __restrict__ srow, const int* __restrict__ endoff,
    const float* __restrict__ dis, const __half* __restrict__ hs_in,
    const __half* __restrict__ x0h, const float* __restrict__ W,
    __half* __restrict__ hs_out, int n)
{
    __shared__ __half WsT[64][72];
    __shared__ __half vs[32][72];
    __shared__ float dcs[32];

    int t = threadIdx.x;
    int w = t >> 6;
    int lane = t & 63;
    int nb = blockIdx.x * 32;

    // --- W^T -> LDS fp16 (coalesced global read, transposed b16 write) ---
    for (int i = t; i < 4096; i += 256) {
        int k = i >> 6, nf = i & 63;
        WsT[nf][k] = __float2half(W[i]);
    }

    // --- gather phase ---
    int j = lane >> 3;       // node slot within wave
    int s = lane & 7;        // feature octet
    int local = w * 8 + j;
    int c = nb + local;
    bool valid = c < n;
    int cc = valid ? c : 0;
    int start = (cc == 0) ? 0 : endoff[cc - 1];
    int end = valid ? endoff[cc] : 0;
    float dc = dis[cc];

    float a0, a1, a2, a3, a4, a5, a6, a7;
    {   // self-loop term (hs_in[c] already dis-scaled)
        f16x8 q = *(const f16x8*)(hs_in + (size_t)cc * 64 + s * 8);
        a0 = (float)q[0]; a1 = (float)q[1]; a2 = (float)q[2]; a3 = (float)q[3];
        a4 = (float)q[4]; a5 = (float)q[5]; a6 = (float)q[6]; a7 = (float)q[7];
    }
    for (int e = start; e < end; e++) {
        int r = srow[e];
        f16x8 q = *(const f16x8*)(hs_in + (size_t)r * 64 + s * 8);
        a0 += (float)q[0]; a1 += (float)q[1]; a2 += (float)q[2]; a3 += (float)q[3];
        a4 += (float)q[4]; a5 += (float)q[5]; a6 += (float)q[6]; a7 += (float)q[7];
    }
    if (valid) {
        float dc9 = (1.0f - ALPHA) * dc;
        f16x8 xv = *(const f16x8*)(x0h + (size_t)cc * 64 + s * 8);
        f16x8 vv;
        vv[0] = (_Float16)(dc9 * a0 + (float)xv[0]);
        vv[1] = (_Float16)(dc9 * a1 + (float)xv[1]);
        vv[2] = (_Float16)(dc9 * a2 + (float)xv[2]);
        vv[3] = (_Float16)(dc9 * a3 + (float)xv[3]);
        vv[4] = (_Float16)(dc9 * a4 + (float)xv[4]);
        vv[5] = (_Float16)(dc9 * a5 + (float)xv[5]);
        vv[6] = (_Float16)(dc9 * a6 + (float)xv[6]);
        vv[7] = (_Float16)(dc9 * a7 + (float)xv[7]);
        *(f16x8*)&vs[local][s * 8] = vv;
        if (s == 0) dcs[local] = dc;
    }
    __syncthreads();

    // --- MFMA phase: wave w -> N-tile w (cols 16w..16w+15) ---
    int m16 = lane & 15;
    int quad = lane >> 4;
#pragma unroll
    for (int mt = 0; mt < 2; mt++) {
        f32x4 acc = {0.0f, 0.0f, 0.0f, 0.0f};
#pragma unroll
        for (int kk = 0; kk < 64; kk += 32) {
            f16x8 af = *(const f16x8*)&vs[mt * 16 + m16][kk + quad * 8];
            f16x8 bf = *(const f16x8*)&WsT[w * 16 + m16][kk + quad * 8];
            acc = __builtin_amdgcn_mfma_f32_16x16x32_f16(af, bf, acc, 0, 0, 0);
        }
#pragma unroll
        for (int r = 0; r < 4; r++) {
            int loc = mt * 16 + quad * 4 + r;
            int cn = nb + loc;
            if (cn < n) {
                float h = fmaxf(acc[r], 0.0f);
                hs_out[(size_t)cn * 64 + w * 16 + m16] = __float2half(dcs[loc] * h);
            }
        }
    }
}

// ================= lin1: t16s = hs @ w1  (dis prescale cancels) =================

__global__ __launch_bounds__(256) void k_lin1(const __half* __restrict__ hs,
                                              const float* __restrict__ w1,
                                              __half* __restrict__ t16s, int n) {
    __shared__ float Ws[64 * 16];
    int t = threadIdx.x;
    for (int i = t; i < 64 * 16; i += 256) Ws[i] = w1[i];
    __syncthreads();
    long long idx = (long long)blockIdx.x * 256 + t;
    int r = (int)(idx >> 4), j = (int)(idx & 15);
    if (r >= n) return;
    const __half* hp = hs + (size_t)r * 64;
    float acc = 0.0f;
#pragma unroll
    for (int k = 0; k < 64; k += 2) {
        float2 u = __half22float2(*(const __half2*)(hp + k));
        acc = fmaf(u.x, Ws[k * 16 + j], acc);
        acc = fmaf(u.y, Ws[(k + 1) * 16 + j], acc);
    }
    t16s[idx] = __float2half(acc);
}

// ================= fused prop16 + lin2 =================

__global__ __launch_bounds__(256) void k_prop16_lin2(
    const int* __restrict__ srow, const int* __restrict__ endoff,
    const float* __restrict__ dis, const __half* __restrict__ t16s,
    const float* __restrict__ b1, const float* __restrict__ w2,
    float* __restrict__ t1s, int n)
{
    int t = threadIdx.x;
    int w = t >> 6, lane = t & 63;
    int g = lane >> 2;   // edge slot 0..15
    int s = lane & 3;    // feature quad 0..3
    int c = blockIdx.x * 4 + w;
    if (c >= n) return;
    int start = (c == 0) ? 0 : endoff[c - 1];
    int end = endoff[c];
    float a0 = 0, a1 = 0, a2 = 0, a3 = 0;
    if (g == 0) {
        float2 q = *(const float2*)(t16s + (size_t)c * 16 + s * 4);
        float2 u;
        u = __half22float2(*(__half2*)&q.x); a0 = u.x; a1 = u.y;
        u = __half22float2(*(__half2*)&q.y); a2 = u.x; a3 = u.y;
    }
    for (int e = start + g; e < end; e += 16) {
        int r = srow[e];
        float2 q = *(const float2*)(t16s + (size_t)r * 16 + s * 4);
        float2 u;
        u = __half22float2(*(__half2*)&q.x); a0 += u.x; a1 += u.y;
        u = __half22float2(*(__half2*)&q.y); a2 += u.x; a3 += u.y;
    }
#pragma unroll
    for (int d = 4; d <= 32; d <<= 1) {
        a0 += __shfl_xor(a0, d, 64); a1 += __shfl_xor(a1, d, 64);
        a2 += __shfl_xor(a2, d, 64); a3 += __shfl_xor(a3, d, 64);
    }
    float dc = dis[c];
    float4 b = *(const float4*)(b1 + s * 4);
    float4 ww = *(const float4*)(w2 + s * 4);
    float partial = (dc * a0 + b.x) * ww.x + (dc * a1 + b.y) * ww.y +
                    (dc * a2 + b.z) * ww.z + (dc * a3 + b.w) * ww.w;
    partial += __shfl_xor(partial, 1, 64);
    partial += __shfl_xor(partial, 2, 64);
    if (lane == 0) t1s[c] = dc * partial;
}

// ================= prop1 + sigmoid =================

__global__ void k_prop1(const int* __restrict__ srow, const int* __restrict__ endoff,
                        const float* __restrict__ dis, const float* __restrict__ t1s,
                        const float* __restrict__ b2, float* __restrict__ out, int n) {
    int c = blockIdx.x * blockDim.x + threadIdx.x;
    if (c >= n) return;
    int start = (c == 0) ? 0 : endoff[c - 1];
    int end = endoff[c];
    float ssum = t1s[c];
    for (int e = start; e < end; e++) ssum += t1s[srow[e]];
    float v = dis[c] * ssum + b2[0];
    out[c] = 1.0f / (1.0f + expf(-v));
}

// ================= launch =================

static inline char* align16(char* p) {
    return (char*)(((uintptr_t)p + 15) & ~(uintptr_t)15);
}

extern "C" void kernel_launch(void* const* d_in, const int* in_sizes, int n_in,
                              void* d_out, int out_size, void* d_ws, size_t ws_size,
                              hipStream_t stream) {
    const float* x  = (const float*)d_in[0];
    const int*   ei = (const int*)d_in[1];
    const float* gw = (const float*)d_in[2];
    const float* w1 = (const float*)d_in[3];
    const float* b1 = (const float*)d_in[4];
    const float* w2 = (const float*)d_in[5];
    const float* b2 = (const float*)d_in[6];
    float* out = (float*)d_out;

    const int N = in_sizes[0] / 64;
    const int E = in_sizes[1] / 2;
    const int L = in_sizes[2] / (64 * 64);

    const int* row = ei;
    const int* col = ei + E;

    char* p = (char*)d_ws;
    int* cnt = (int*)p;            p = align16(p + (size_t)N * 4);
    int* off = (int*)p;            p = align16(p + (size_t)N * 4);
    int* bsum = (int*)p;           p = align16(p + 4096);
    float* dis = (float*)p;        p = align16(p + (size_t)N * 4);
    int* srow = (int*)p;           p = align16(p + (size_t)E * 4);
    __half* hsA = (__half*)p;      p = align16(p + (size_t)N * 128);
    __half* hsB = (__half*)p;      p = align16(p + (size_t)N * 128);
    __half* x0h = (__half*)p;      p = align16(p + (size_t)N * 128);
    __half* t16s = (__half*)p;     p = align16(p + (size_t)N * 32);
    float* t1s = (float*)p;

    const int B = 256;
    int gN = (N + B - 1) / B;
    int gE = (E + B - 1) / B;
    int nb = (N + 255) / 256;

    // CSR + normalization
    k_zero<<<gN, B, 0, stream>>>(cnt, N);
    k_count<<<gE, B, 0, stream>>>(col, cnt, E);
    k_dis<<<gN, B, 0, stream>>>(cnt, dis, N);
    k_scan_block<<<nb, 256, 0, stream>>>(cnt, off, bsum, N);
    k_scan_bsum<<<1, 512, 0, stream>>>(bsum, nb);
    k_scan_add<<<nb, 256, 0, stream>>>(off, bsum, N);
    k_scatter<<<gE, B, 0, stream>>>(row, col, off, srow, E);

    // prescale x -> hsA (fp16, dis-scaled) and x0h (fp16, alpha-scaled)
    long long tot64 = (long long)N * 64;
    k_prescale<<<(int)((tot64 + B - 1) / B), B, 0, stream>>>(x, dis, hsA, x0h, tot64);

    // GCN2 stack
    __half* bufs[2] = {hsA, hsB};
    const __half* hin = hsA;
    for (int l = 0; l < L; l++) {
        __half* hout = bufs[(l + 1) & 1];
        k_gcn2_fused<<<(N + 31) / 32, B, 0, stream>>>(srow, off, dis, hin, x0h,
                                                      gw + (long long)l * 64 * 64, hout, N);
        hin = hout;
    }

    // GCNConv(64->16)
    k_lin1<<<(int)(((long long)N * 16 + B - 1) / B), B, 0, stream>>>(hin, w1, t16s, N);
    // fused propagate16 + lin2
    k_prop16_lin2<<<(N + 3) / 4, B, 0, stream>>>(srow, off, dis, t16s, b1, w2, t1s, N);
    // propagate1 + bias + sigmoid
    k_prop1<<<gN, B, 0, stream>>>(srow, off, dis, t1s, b2, out, N);
}

// Round 5
// 354.422 us; speedup vs baseline: 3.8241x; 1.0774x over previous
//
#include <hip/hip_runtime.h>
#include <hip/hip_fp16.h>
#include <math.h>

#define ALPHA 0.1f
#define CHUNK 8192

typedef _Float16 f16x8 __attribute__((ext_vector_type(8)));
typedef float f32x4 __attribute__((ext_vector_type(4)));

// ================= bucketed CSR build =================
// Bucket = col >> 7 (128 nodes per bucket). NB <= 1024 (N <= 131072).

__global__ void k_zero(int* a, int n) {
    int i = blockIdx.x * blockDim.x + threadIdx.x;
    if (i < n) a[i] = 0;
}

// P1: per-block LDS histogram -> global bucket totals
__global__ __launch_bounds__(256) void kb_hist(const int* __restrict__ col, int e,
                                               int nbuck, int* __restrict__ tot) {
    __shared__ int h[1024];
    int t = threadIdx.x;
    for (int i = t; i < 1024; i += 256) h[i] = 0;
    __syncthreads();
    int base = blockIdx.x * CHUNK;
    int end = min(base + CHUNK, e);
    for (int i = base + t; i < end; i += 256)
        atomicAdd(&h[col[i] >> 7], 1);
    __syncthreads();
    for (int i = t; i < nbuck; i += 256)
        if (h[i]) atomicAdd(&tot[i], h[i]);
}

// P2: scan bucket totals -> start[] (exclusive; start[nbuck]=E), cursor copy
__global__ __launch_bounds__(1024) void kb_scan(const int* __restrict__ tot,
                                                int* __restrict__ start,
                                                int* __restrict__ cursor, int nbuck) {
    __shared__ int s[1024];
    int t = threadIdx.x;
    int v = (t < nbuck) ? tot[t] : 0;
    s[t] = v;
    __syncthreads();
    for (int d = 1; d < 1024; d <<= 1) {
        int add = (t >= d) ? s[t - d] : 0;
        __syncthreads();
        s[t] += add;
        __syncthreads();
    }
    if (t < nbuck) { start[t] = s[t] - v; cursor[t] = s[t] - v; }
    if (t == nbuck - 1) start[nbuck] = s[t];
}

// P3: partition edges into bucket regions as packed ints (collow<<17 | row)
__global__ __launch_bounds__(256) void kb_part(const int* __restrict__ row,
                                               const int* __restrict__ col,
                                               int e, int nbuck,
                                               int* __restrict__ cursor,
                                               int* __restrict__ part) {
    __shared__ int lcnt[1024];
    __shared__ int lbase[1024];
    int t = threadIdx.x;
    for (int i = t; i < 1024; i += 256) lcnt[i] = 0;
    __syncthreads();
    int base = blockIdx.x * CHUNK;
    int end = min(base + CHUNK, e);
    for (int i = base + t; i < end; i += 256)
        atomicAdd(&lcnt[col[i] >> 7], 1);
    __syncthreads();
    for (int i = t; i < nbuck; i += 256) {
        int c = lcnt[i];
        lbase[i] = c ? atomicAdd(&cursor[i], c) : 0;
    }
    __syncthreads();
    for (int i = t; i < 1024; i += 256) lcnt[i] = 0;
    __syncthreads();
    for (int i = base + t; i < end; i += 256) {
        int cl = col[i];
        int b = cl >> 7;
        int lp = atomicAdd(&lcnt[b], 1);
        part[lbase[b] + lp] = ((cl & 127) << 17) | row[i];
    }
}

// P4: per-bucket local CSR (count/scan/scatter in LDS), write srow/off/dis
__global__ __launch_bounds__(256) void kb_csr(const int* __restrict__ start,
                                              const int* __restrict__ part, int n,
                                              float* __restrict__ dis,
                                              int* __restrict__ off,
                                              int* __restrict__ srow) {
    __shared__ int cnt[128], excl[128], stmp[128];
    int b = blockIdx.x;
    int t = threadIdx.x;
    int bstart = start[b], bend = start[b + 1];
    if (t < 128) cnt[t] = 0;
    __syncthreads();
    for (int i = bstart + t; i < bend; i += 256)
        atomicAdd(&cnt[part[i] >> 17], 1);
    __syncthreads();
    if (t < 128) stmp[t] = cnt[t];
    __syncthreads();
    for (int d = 1; d < 128; d <<= 1) {
        int add = (t < 128 && t >= d) ? stmp[t - d] : 0;
        __syncthreads();
        if (t < 128) stmp[t] += add;
        __syncthreads();
    }
    if (t < 128) {
        excl[t] = stmp[t] - cnt[t];
        int c = (b << 7) + t;
        if (c < n) {
            off[c] = bstart + stmp[t];                 // inclusive end offset
            dis[c] = rsqrtf((float)cnt[t] + 1.0f);     // +1 self-loop
        }
        cnt[t] = 0;  // reuse as scatter cursor
    }
    __syncthreads();
    for (int i = bstart + t; i < bend; i += 256) {
        int pk = part[i];
        int cl = pk >> 17;
        int lp = atomicAdd(&cnt[cl], 1);
        srow[bstart + excl[cl] + lp] = pk & 0x1FFFF;
    }
}

// ================= prescale =================
__global__ void k_prescale(const float* __restrict__ x, const float* __restrict__ dis,
                           __half* __restrict__ xs, __half* __restrict__ x0h,
                           long long total) {
    long long i = (long long)blockIdx.x * blockDim.x + threadIdx.x;
    if (i >= total) return;
    float xv = x[i];
    float d = dis[i >> 6];
    xs[i] = __float2half(d * xv);
    x0h[i] = __float2half(ALPHA * xv);
}

// ================= fused GCN2 layer (MFMA) =================

__global__ __launch_bounds__(256) void k_gcn2_fused(
    const int* __restrict__ srow, const int* __restrict__ endoff,
    const float* __restrict__ dis, const __half* __restrict__ hs_in,
    const __half* __restrict__ x0h, const float* __restrict__ W,
    __half* __restrict__ hs_out, int n)
{
    __shared__ __half WsT[64][72];
    __shared__ __half vs[32][72];
    __shared__ float dcs[32];

    int t = threadIdx.x;
    int w = t >> 6;
    int lane = t & 63;
    int nb = blockIdx.x * 32;

    for (int i = t; i < 4096; i += 256) {
        int k = i >> 6, nf = i & 63;
        WsT[nf][k] = __float2half(W[i]);
    }

    int j = lane >> 3;
    int s = lane & 7;
    int local = w * 8 + j;
    int c = nb + local;
    bool valid = c < n;
    int cc = valid ? c : 0;
    int start = (cc == 0) ? 0 : endoff[cc - 1];
    int end = valid ? endoff[cc] : 0;
    float dc = dis[cc];

    float a0, a1, a2, a3, a4, a5, a6, a7;
    {
        f16x8 q = *(const f16x8*)(hs_in + (size_t)cc * 64 + s * 8);
        a0 = (float)q[0]; a1 = (float)q[1]; a2 = (float)q[2]; a3 = (float)q[3];
        a4 = (float)q[4]; a5 = (float)q[5]; a6 = (float)q[6]; a7 = (float)q[7];
    }
    for (int e = start; e < end; e++) {
        int r = srow[e];
        f16x8 q = *(const f16x8*)(hs_in + (size_t)r * 64 + s * 8);
        a0 += (float)q[0]; a1 += (float)q[1]; a2 += (float)q[2]; a3 += (float)q[3];
        a4 += (float)q[4]; a5 += (float)q[5]; a6 += (float)q[6]; a7 += (float)q[7];
    }
    if (valid) {
        float dc9 = (1.0f - ALPHA) * dc;
        f16x8 xv = *(const f16x8*)(x0h + (size_t)cc * 64 + s * 8);
        f16x8 vv;
        vv[0] = (_Float16)(dc9 * a0 + (float)xv[0]);
        vv[1] = (_Float16)(dc9 * a1 + (float)xv[1]);
        vv[2] = (_Float16)(dc9 * a2 + (float)xv[2]);
        vv[3] = (_Float16)(dc9 * a3 + (float)xv[3]);
        vv[4] = (_Float16)(dc9 * a4 + (float)xv[4]);
        vv[5] = (_Float16)(dc9 * a5 + (float)xv[5]);
        vv[6] = (_Float16)(dc9 * a6 + (float)xv[6]);
        vv[7] = (_Float16)(dc9 * a7 + (float)xv[7]);
        *(f16x8*)&vs[local][s * 8] = vv;
        if (s == 0) dcs[local] = dc;
    }
    __syncthreads();

    int m16 = lane & 15;
    int quad = lane >> 4;
#pragma unroll
    for (int mt = 0; mt < 2; mt++) {
        f32x4 acc = {0.0f, 0.0f, 0.0f, 0.0f};
#pragma unroll
        for (int kk = 0; kk < 64; kk += 32) {
            f16x8 af = *(const f16x8*)&vs[mt * 16 + m16][kk + quad * 8];
            f16x8 bf = *(const f16x8*)&WsT[w * 16 + m16][kk + quad * 8];
            acc = __builtin_amdgcn_mfma_f32_16x16x32_f16(af, bf, acc, 0, 0, 0);
        }
#pragma unroll
        for (int r = 0; r < 4; r++) {
            int loc = mt * 16 + quad * 4 + r;
            int cn = nb + loc;
            if (cn < n) {
                float h = fmaxf(acc[r], 0.0f);
                hs_out[(size_t)cn * 64 + w * 16 + m16] = __float2half(dcs[loc] * h);
            }
        }
    }
}

// ================= lin1 =================

__global__ __launch_bounds__(256) void k_lin1(const __half* __restrict__ hs,
                                              const float* __restrict__ w1,
                                              __half* __restrict__ t16s, int n) {
    __shared__ float Ws[64 * 16];
    int t = threadIdx.x;
    for (int i = t; i < 64 * 16; i += 256) Ws[i] = w1[i];
    __syncthreads();
    long long idx = (long long)blockIdx.x * 256 + t;
    int r = (int)(idx >> 4), j = (int)(idx & 15);
    if (r >= n) return;
    const __half* hp = hs + (size_t)r * 64;
    float acc = 0.0f;
#pragma unroll
    for (int k = 0; k < 64; k += 2) {
        float2 u = __half22float2(*(const __half2*)(hp + k));
        acc = fmaf(u.x, Ws[k * 16 + j], acc);
        acc = fmaf(u.y, Ws[(k + 1) * 16 + j], acc);
    }
    t16s[idx] = __float2half(acc);
}

// ================= fused prop16 + lin2 =================

__global__ __launch_bounds__(256) void k_prop16_lin2(
    const int* __restrict__ srow, const int* __restrict__ endoff,
    const float* __restrict__ dis, const __half* __restrict__ t16s,
    const float* __restrict__ b1, const float* __restrict__ w2,
    float* __restrict__ t1s, int n)
{
    int t = threadIdx.x;
    int w = t >> 6, lane = t & 63;
    int g = lane >> 2;
    int s = lane & 3;
    int c = blockIdx.x * 4 + w;
    if (c >= n) return;
    int start = (c == 0) ? 0 : endoff[c - 1];
    int end = endoff[c];
    float a0 = 0, a1 = 0, a2 = 0, a3 = 0;
    if (g == 0) {
        float2 q = *(const float2*)(t16s + (size_t)c * 16 + s * 4);
        float2 u;
        u = __half22float2(*(__half2*)&q.x); a0 = u.x; a1 = u.y;
        u = __half22float2(*(__half2*)&q.y); a2 = u.x; a3 = u.y;
    }
    for (int e = start + g; e < end; e += 16) {
        int r = srow[e];
        float2 q = *(const float2*)(t16s + (size_t)r * 16 + s * 4);
        float2 u;
        u = __half22float2(*(__half2*)&q.x); a0 += u.x; a1 += u.y;
        u = __half22float2(*(__half2*)&q.y); a2 += u.x; a3 += u.y;
    }
#pragma unroll
    for (int d = 4; d <= 32; d <<= 1) {
        a0 += __shfl_xor(a0, d, 64); a1 += __shfl_xor(a1, d, 64);
        a2 += __shfl_xor(a2, d, 64); a3 += __shfl_xor(a3, d, 64);
    }
    float dc = dis[c];
    float4 b = *(const float4*)(b1 + s * 4);
    float4 ww = *(const float4*)(w2 + s * 4);
    float partial = (dc * a0 + b.x) * ww.x + (dc * a1 + b.y) * ww.y +
                    (dc * a2 + b.z) * ww.z + (dc * a3 + b.w) * ww.w;
    partial += __shfl_xor(partial, 1, 64);
    partial += __shfl_xor(partial, 2, 64);
    if (lane == 0) t1s[c] = dc * partial;
}

// ================= prop1 + sigmoid =================

__global__ void k_prop1(const int* __restrict__ srow, const int* __restrict__ endoff,
                        const float* __restrict__ dis, const float* __restrict__ t1s,
                        const float* __restrict__ b2, float* __restrict__ out, int n) {
    int c = blockIdx.x * blockDim.x + threadIdx.x;
    if (c >= n) return;
    int start = (c == 0) ? 0 : endoff[c - 1];
    int end = endoff[c];
    float ssum = t1s[c];
    for (int e = start; e < end; e++) ssum += t1s[srow[e]];
    float v = dis[c] * ssum + b2[0];
    out[c] = 1.0f / (1.0f + expf(-v));
}

// ================= launch =================

static inline char* align16(char* p) {
    return (char*)(((uintptr_t)p + 15) & ~(uintptr_t)15);
}

extern "C" void kernel_launch(void* const* d_in, const int* in_sizes, int n_in,
                              void* d_out, int out_size, void* d_ws, size_t ws_size,
                              hipStream_t stream) {
    const float* x  = (const float*)d_in[0];
    const int*   ei = (const int*)d_in[1];
    const float* gw = (const float*)d_in[2];
    const float* w1 = (const float*)d_in[3];
    const float* b1 = (const float*)d_in[4];
    const float* w2 = (const float*)d_in[5];
    const float* b2 = (const float*)d_in[6];
    float* out = (float*)d_out;

    const int N = in_sizes[0] / 64;
    const int E = in_sizes[1] / 2;
    const int L = in_sizes[2] / (64 * 64);

    const int* row = ei;
    const int* col = ei + E;

    const int NB = (N + 127) >> 7;   // buckets of 128 nodes (NB <= 1024)

    char* p = (char*)d_ws;
    int* off = (int*)p;            p = align16(p + (size_t)N * 4);
    float* dis = (float*)p;        p = align16(p + (size_t)N * 4);
    int* srow = (int*)p;           p = align16(p + (size_t)E * 4);
    int* bstart = (int*)p;         p = align16(p + (size_t)(NB + 1) * 4);
    int* bcur = (int*)p;           p = align16(p + (size_t)NB * 4);
    int* btot = (int*)p;           p = align16(p + (size_t)NB * 4);
    __half* hsA = (__half*)p;      p = align16(p + (size_t)N * 128);
    __half* hsB = (__half*)p;      p = align16(p + (size_t)N * 128);
    __half* x0h = (__half*)p;      p = align16(p + (size_t)N * 128);
    __half* t16s = (__half*)p;     p = align16(p + (size_t)N * 32);
    float* t1s = (float*)p;
    int* part = (int*)hsB;         // alias: consumed by kb_csr before hsB is written

    const int B = 256;
    int gN = (N + B - 1) / B;
    int gPart = (E + CHUNK - 1) / CHUNK;

    // CSR build (bucketed counting sort)
    k_zero<<<(NB + B - 1) / B, B, 0, stream>>>(btot, NB);
    kb_hist<<<gPart, B, 0, stream>>>(col, E, NB, btot);
    kb_scan<<<1, 1024, 0, stream>>>(btot, bstart, bcur, NB);
    kb_part<<<gPart, B, 0, stream>>>(row, col, E, NB, bcur, part);
    kb_csr<<<NB, B, 0, stream>>>(bstart, part, N, dis, off, srow);

    // prescale
    long long tot64 = (long long)N * 64;
    k_prescale<<<(int)((tot64 + B - 1) / B), B, 0, stream>>>(x, dis, hsA, x0h, tot64);

    // GCN2 stack
    __half* bufs[2] = {hsA, hsB};
    const __half* hin = hsA;
    for (int l = 0; l < L; l++) {
        __half* hout = bufs[(l + 1) & 1];
        k_gcn2_fused<<<(N + 31) / 32, B, 0, stream>>>(srow, off, dis, hin, x0h,
                                                      gw + (long long)l * 64 * 64, hout, N);
        hin = hout;
    }

    // GCNConv(64->16)
    k_lin1<<<(int)(((long long)N * 16 + B - 1) / B), B, 0, stream>>>(hin, w1, t16s, N);
    k_prop16_lin2<<<(N + 3) / 4, B, 0, stream>>>(srow, off, dis, t16s, b1, w2, t1s, N);
    k_prop1<<<gN, B, 0, stream>>>(srow, off, dis, t1s, b2, out, N);
}

// Round 6
// 338.709 us; speedup vs baseline: 4.0015x; 1.0464x over previous
//
#include <hip/hip_runtime.h>
#include <hip/hip_fp16.h>
#include <math.h>

#define ALPHA 0.1f
#define CHUNK 8192

typedef _Float16 f16x8 __attribute__((ext_vector_type(8)));
typedef float f32x4 __attribute__((ext_vector_type(4)));

// ================= bucketed CSR build =================
// Bucket = col >> 7 (128 nodes per bucket). NB <= 1024 (N <= 131072).

__global__ void k_zero(int* a, int n) {
    int i = blockIdx.x * blockDim.x + threadIdx.x;
    if (i < n) a[i] = 0;
}

__global__ __launch_bounds__(256) void kb_hist(const int* __restrict__ col, int e,
                                               int nbuck, int* __restrict__ tot) {
    __shared__ int h[1024];
    int t = threadIdx.x;
    for (int i = t; i < 1024; i += 256) h[i] = 0;
    __syncthreads();
    int base = blockIdx.x * CHUNK;
    int end = min(base + CHUNK, e);
    for (int i = base + t; i < end; i += 256)
        atomicAdd(&h[col[i] >> 7], 1);
    __syncthreads();
    for (int i = t; i < nbuck; i += 256)
        if (h[i]) atomicAdd(&tot[i], h[i]);
}

__global__ __launch_bounds__(1024) void kb_scan(const int* __restrict__ tot,
                                                int* __restrict__ start,
                                                int* __restrict__ cursor, int nbuck) {
    __shared__ int s[1024];
    int t = threadIdx.x;
    int v = (t < nbuck) ? tot[t] : 0;
    s[t] = v;
    __syncthreads();
    for (int d = 1; d < 1024; d <<= 1) {
        int add = (t >= d) ? s[t - d] : 0;
        __syncthreads();
        s[t] += add;
        __syncthreads();
    }
    if (t < nbuck) { start[t] = s[t] - v; cursor[t] = s[t] - v; }
    if (t == nbuck - 1) start[nbuck] = s[t];
}

__global__ __launch_bounds__(256) void kb_part(const int* __restrict__ row,
                                               const int* __restrict__ col,
                                               int e, int nbuck,
                                               int* __restrict__ cursor,
                                               int* __restrict__ part) {
    __shared__ int lcnt[1024];
    __shared__ int lbase[1024];
    int t = threadIdx.x;
    for (int i = t; i < 1024; i += 256) lcnt[i] = 0;
    __syncthreads();
    int base = blockIdx.x * CHUNK;
    int end = min(base + CHUNK, e);
    for (int i = base + t; i < end; i += 256)
        atomicAdd(&lcnt[col[i] >> 7], 1);
    __syncthreads();
    for (int i = t; i < nbuck; i += 256) {
        int c = lcnt[i];
        lbase[i] = c ? atomicAdd(&cursor[i], c) : 0;
    }
    __syncthreads();
    for (int i = t; i < 1024; i += 256) lcnt[i] = 0;
    __syncthreads();
    for (int i = base + t; i < end; i += 256) {
        int cl = col[i];
        int b = cl >> 7;
        int lp = atomicAdd(&lcnt[b], 1);
        part[lbase[b] + lp] = ((cl & 127) << 17) | row[i];
    }
}

// P4: per-bucket local CSR + fused prescale of the bucket's 128 nodes.
__global__ __launch_bounds__(256) void kb_csr(const int* __restrict__ start,
                                              const int* __restrict__ part, int n,
                                              const float* __restrict__ x,
                                              float* __restrict__ dis,
                                              int* __restrict__ off,
                                              int* __restrict__ srow,
                                              __half* __restrict__ xs,
                                              __half* __restrict__ x0h) {
    __shared__ int cnt[128], excl[128], stmp[128];
    __shared__ float disl[128];
    int b = blockIdx.x;
    int t = threadIdx.x;
    int bstart = start[b], bend = start[b + 1];
    if (t < 128) cnt[t] = 0;
    __syncthreads();
    for (int i = bstart + t; i < bend; i += 256)
        atomicAdd(&cnt[part[i] >> 17], 1);
    __syncthreads();
    if (t < 128) stmp[t] = cnt[t];
    __syncthreads();
    for (int d = 1; d < 128; d <<= 1) {
        int add = (t < 128 && t >= d) ? stmp[t - d] : 0;
        __syncthreads();
        if (t < 128) stmp[t] += add;
        __syncthreads();
    }
    if (t < 128) {
        excl[t] = stmp[t] - cnt[t];
        int c = (b << 7) + t;
        float d = rsqrtf((float)cnt[t] + 1.0f);
        disl[t] = d;
        if (c < n) {
            off[c] = bstart + stmp[t];             // inclusive end offset
            dis[c] = d;
        }
        cnt[t] = 0;  // reuse as scatter cursor
    }
    __syncthreads();
    for (int i = bstart + t; i < bend; i += 256) {
        int pk = part[i];
        int cl = pk >> 17;
        int lp = atomicAdd(&cnt[cl], 1);
        srow[bstart + excl[cl] + lp] = pk & 0x1FFFF;
    }
    // fused prescale: nodes b*128 .. b*128+127
    int c0 = b << 7;
    for (int i = t; i < 128 * 64; i += 256) {
        int node = c0 + (i >> 6);
        if (node >= n) break;
        float xv = x[(size_t)node * 64 + (i & 63)];
        float d = disl[i >> 6];
        xs[(size_t)node * 64 + (i & 63)] = __float2half(d * xv);
        x0h[(size_t)node * 64 + (i & 63)] = __float2half(ALPHA * xv);
    }
}

// ================= weight prep: fp16 transposed =================
// whT[l][nf][k] = gw[l][k][nf]  (4 layers, 64x64)
// w1T[nf][k]   = w1[k][nf]      (16x64)

__global__ void k_prep(const float* __restrict__ gw, const float* __restrict__ w1,
                       __half* __restrict__ whT, __half* __restrict__ w1T, int L) {
    int i = blockIdx.x * blockDim.x + threadIdx.x;
    int tot = L * 4096;
    if (i < tot) {
        int l = i >> 12, r = i & 4095;
        int k = r >> 6, nf = r & 63;
        whT[(l << 12) + nf * 64 + k] = __float2half(gw[i]);
    } else if (i < tot + 1024) {
        int r = i - tot;
        int k = r >> 4, nf = r & 15;
        w1T[nf * 64 + k] = __float2half(w1[r]);
    }
}

// ================= fused GCN2 layer (MFMA, B-frags from global) =================

__global__ __launch_bounds__(256) void k_gcn2_fused(
    const int* __restrict__ srow, const int* __restrict__ endoff,
    const float* __restrict__ dis, const __half* __restrict__ hs_in,
    const __half* __restrict__ x0h, const __half* __restrict__ whT,
    __half* __restrict__ hs_out,           // null on last layer
    const __half* __restrict__ w1T,        // non-null on last layer
    __half* __restrict__ t16s, int n)
{
    __shared__ __half vs[32][72];
    __shared__ __half vs2[32][72];
    __shared__ float dcs[32];

    int t = threadIdx.x;
    int w = t >> 6;
    int lane = t & 63;
    int nb = blockIdx.x * 32;

    // --- gather phase: lane = (node slot j, feature octet s) ---
    int j = lane >> 3;
    int s = lane & 7;
    int local = w * 8 + j;
    int c = nb + local;
    bool valid = c < n;
    int cc = valid ? c : 0;
    int start = (cc == 0) ? 0 : endoff[cc - 1];
    int end = valid ? endoff[cc] : 0;
    float dc = dis[cc];

    float a0, a1, a2, a3, a4, a5, a6, a7;
    float b0 = 0, b1 = 0, b2 = 0, b3 = 0, b4 = 0, b5 = 0, b6 = 0, b7 = 0;
    {   // self-loop term (hs_in[c] already dis-scaled)
        f16x8 q = *(const f16x8*)(hs_in + (size_t)cc * 64 + s * 8);
        a0 = (float)q[0]; a1 = (float)q[1]; a2 = (float)q[2]; a3 = (float)q[3];
        a4 = (float)q[4]; a5 = (float)q[5]; a6 = (float)q[6]; a7 = (float)q[7];
    }
    int e = start;
    for (; e + 2 <= end; e += 2) {
        int r0 = srow[e];
        int r1 = srow[e + 1];
        f16x8 q0 = *(const f16x8*)(hs_in + (size_t)r0 * 64 + s * 8);
        f16x8 q1 = *(const f16x8*)(hs_in + (size_t)r1 * 64 + s * 8);
        a0 += (float)q0[0]; a1 += (float)q0[1]; a2 += (float)q0[2]; a3 += (float)q0[3];
        a4 += (float)q0[4]; a5 += (float)q0[5]; a6 += (float)q0[6]; a7 += (float)q0[7];
        b0 += (float)q1[0]; b1 += (float)q1[1]; b2 += (float)q1[2]; b3 += (float)q1[3];
        b4 += (float)q1[4]; b5 += (float)q1[5]; b6 += (float)q1[6]; b7 += (float)q1[7];
    }
    if (e < end) {
        int r0 = srow[e];
        f16x8 q0 = *(const f16x8*)(hs_in + (size_t)r0 * 64 + s * 8);
        a0 += (float)q0[0]; a1 += (float)q0[1]; a2 += (float)q0[2]; a3 += (float)q0[3];
        a4 += (float)q0[4]; a5 += (float)q0[5]; a6 += (float)q0[6]; a7 += (float)q0[7];
    }
    a0 += b0; a1 += b1; a2 += b2; a3 += b3;
    a4 += b4; a5 += b5; a6 += b6; a7 += b7;

    if (valid) {
        float dc9 = (1.0f - ALPHA) * dc;
        const f16x8* xp = (const f16x8*)(x0h + (size_t)cc * 64 + s * 8);
        f16x8 xv = __builtin_nontemporal_load(xp);
        f16x8 vv;
        vv[0] = (_Float16)(dc9 * a0 + (float)xv[0]);
        vv[1] = (_Float16)(dc9 * a1 + (float)xv[1]);
        vv[2] = (_Float16)(dc9 * a2 + (float)xv[2]);
        vv[3] = (_Float16)(dc9 * a3 + (float)xv[3]);
        vv[4] = (_Float16)(dc9 * a4 + (float)xv[4]);
        vv[5] = (_Float16)(dc9 * a5 + (float)xv[5]);
        vv[6] = (_Float16)(dc9 * a6 + (float)xv[6]);
        vv[7] = (_Float16)(dc9 * a7 + (float)xv[7]);
        *(f16x8*)&vs[local][s * 8] = vv;
        if (s == 0) dcs[local] = dc;
    }
    __syncthreads();

    // --- MFMA phase: wave w -> cols 16w..16w+15; B-frags from global whT ---
    int m16 = lane & 15;
    int quad = lane >> 4;
    f16x8 bf0 = *(const f16x8*)(whT + (size_t)(w * 16 + m16) * 64 + quad * 8);
    f16x8 bf1 = *(const f16x8*)(whT + (size_t)(w * 16 + m16) * 64 + 32 + quad * 8);
    bool last = (w1T != nullptr);
#pragma unroll
    for (int mt = 0; mt < 2; mt++) {
        f32x4 acc = {0.0f, 0.0f, 0.0f, 0.0f};
        f16x8 af0 = *(const f16x8*)&vs[mt * 16 + m16][quad * 8];
        f16x8 af1 = *(const f16x8*)&vs[mt * 16 + m16][32 + quad * 8];
        acc = __builtin_amdgcn_mfma_f32_16x16x32_f16(af0, bf0, acc, 0, 0, 0);
        acc = __builtin_amdgcn_mfma_f32_16x16x32_f16(af1, bf1, acc, 0, 0, 0);
        if (!last) {
#pragma unroll
            for (int r = 0; r < 4; r++) {
                int loc = mt * 16 + quad * 4 + r;
                int cn = nb + loc;
                if (cn < n) {
                    float h = fmaxf(acc[r], 0.0f);
                    hs_out[(size_t)cn * 64 + w * 16 + m16] = __float2half(dcs[loc] * h);
                }
            }
        } else {
#pragma unroll
            for (int r = 0; r < 4; r++) {
                int loc = mt * 16 + quad * 4 + r;
                vs2[loc][w * 16 + m16] = __float2half(fmaxf(acc[r], 0.0f));
            }
        }
    }

    // --- last layer: fused lin1 (t16s = dis * (h @ w1)) on waves 0,1 ---
    if (last) {
        __syncthreads();
        if (w < 2) {
            f16x8 c0 = *(const f16x8*)(w1T + (size_t)m16 * 64 + quad * 8);
            f16x8 c1 = *(const f16x8*)(w1T + (size_t)m16 * 64 + 32 + quad * 8);
            f16x8 af0 = *(const f16x8*)&vs2[w * 16 + m16][quad * 8];
            f16x8 af1 = *(const f16x8*)&vs2[w * 16 + m16][32 + quad * 8];
            f32x4 acc = {0.0f, 0.0f, 0.0f, 0.0f};
            acc = __builtin_amdgcn_mfma_f32_16x16x32_f16(af0, c0, acc, 0, 0, 0);
            acc = __builtin_amdgcn_mfma_f32_16x16x32_f16(af1, c1, acc, 0, 0, 0);
#pragma unroll
            for (int r = 0; r < 4; r++) {
                int loc = w * 16 + quad * 4 + r;
                int cn = nb + loc;
                if (cn < n)
                    t16s[(size_t)cn * 16 + m16] = __float2half(dcs[loc] * acc[r]);
            }
        }
    }
}

// ================= fused prop16 + lin2 =================

__global__ __launch_bounds__(256) void k_prop16_lin2(
    const int* __restrict__ srow, const int* __restrict__ endoff,
    const float* __restrict__ dis, const __half* __restrict__ t16s,
    const float* __restrict__ b1, const float* __restrict__ w2,
    float* __restrict__ t1s, int n)
{
    int t = threadIdx.x;
    int w = t >> 6, lane = t & 63;
    int g = lane >> 2;
    int s = lane & 3;
    int c = blockIdx.x * 4 + w;
    if (c >= n) return;
    int start = (c == 0) ? 0 : endoff[c - 1];
    int end = endoff[c];
    float a0 = 0, a1 = 0, a2 = 0, a3 = 0;
    if (g == 0) {
        float2 q = *(const float2*)(t16s + (size_t)c * 16 + s * 4);
        float2 u;
        u = __half22float2(*(__half2*)&q.x); a0 = u.x; a1 = u.y;
        u = __half22float2(*(__half2*)&q.y); a2 = u.x; a3 = u.y;
    }
    for (int e = start + g; e < end; e += 16) {
        int r = srow[e];
        float2 q = *(const float2*)(t16s + (size_t)r * 16 + s * 4);
        float2 u;
        u = __half22float2(*(__half2*)&q.x); a0 += u.x; a1 += u.y;
        u = __half22float2(*(__half2*)&q.y); a2 += u.x; a3 += u.y;
    }
#pragma unroll
    for (int d = 4; d <= 32; d <<= 1) {
        a0 += __shfl_xor(a0, d, 64); a1 += __shfl_xor(a1, d, 64);
        a2 += __shfl_xor(a2, d, 64); a3 += __shfl_xor(a3, d, 64);
    }
    float dc = dis[c];
    float4 b = *(const float4*)(b1 + s * 4);
    float4 ww = *(const float4*)(w2 + s * 4);
    float partial = (dc * a0 + b.x) * ww.x + (dc * a1 + b.y) * ww.y +
                    (dc * a2 + b.z) * ww.z + (dc * a3 + b.w) * ww.w;
    partial += __shfl_xor(partial, 1, 64);
    partial += __shfl_xor(partial, 2, 64);
    if (lane == 0) t1s[c] = dc * partial;
}

// ================= prop1 + sigmoid =================

__global__ void k_prop1(const int* __restrict__ srow, const int* __restrict__ endoff,
                        const float* __restrict__ dis, const float* __restrict__ t1s,
                        const float* __restrict__ b2, float* __restrict__ out, int n) {
    int c = blockIdx.x * blockDim.x + threadIdx.x;
    if (c >= n) return;
    int start = (c == 0) ? 0 : endoff[c - 1];
    int end = endoff[c];
    float ssum = t1s[c];
    for (int e = start; e < end; e++) ssum += t1s[srow[e]];
    float v = dis[c] * ssum + b2[0];
    out[c] = 1.0f / (1.0f + expf(-v));
}

// ================= launch =================

static inline char* align16(char* p) {
    return (char*)(((uintptr_t)p + 15) & ~(uintptr_t)15);
}

extern "C" void kernel_launch(void* const* d_in, const int* in_sizes, int n_in,
                              void* d_out, int out_size, void* d_ws, size_t ws_size,
                              hipStream_t stream) {
    const float* x  = (const float*)d_in[0];
    const int*   ei = (const int*)d_in[1];
    const float* gw = (const float*)d_in[2];
    const float* w1 = (const float*)d_in[3];
    const float* b1 = (const float*)d_in[4];
    const float* w2 = (const float*)d_in[5];
    const float* b2 = (const float*)d_in[6];
    float* out = (float*)d_out;

    const int N = in_sizes[0] / 64;
    const int E = in_sizes[1] / 2;
    const int L = in_sizes[2] / (64 * 64);

    const int* row = ei;
    const int* col = ei + E;

    const int NB = (N + 127) >> 7;

    char* p = (char*)d_ws;
    int* off = (int*)p;            p = align16(p + (size_t)N * 4);
    float* dis = (float*)p;        p = align16(p + (size_t)N * 4);
    int* srow = (int*)p;           p = align16(p + (size_t)E * 4);
    int* bstart = (int*)p;         p = align16(p + (size_t)(NB + 1) * 4);
    int* bcur = (int*)p;           p = align16(p + (size_t)NB * 4);
    int* btot = (int*)p;           p = align16(p + (size_t)NB * 4);
    __half* whT = (__half*)p;      p = align16(p + (size_t)L * 4096 * 2);
    __half* w1T = (__half*)p;      p = align16(p + 1024 * 2);
    __half* hsA = (__half*)p;      p = align16(p + (size_t)N * 128);
    __half* hsB = (__half*)p;      p = align16(p + (size_t)N * 128);
    __half* x0h = (__half*)p;      p = align16(p + (size_t)N * 128);
    __half* t16s = (__half*)p;     p = align16(p + (size_t)N * 32);
    float* t1s = (float*)p;
    int* part = (int*)hsB;         // alias: consumed by kb_csr before hsB is written

    const int B = 256;
    int gN = (N + B - 1) / B;
    int gPart = (E + CHUNK - 1) / CHUNK;

    // weight prep (independent of CSR)
    k_prep<<<(L * 4096 + 1024 + B - 1) / B, B, 0, stream>>>(gw, w1, whT, w1T, L);

    // CSR build (bucketed counting sort) + fused prescale
    k_zero<<<(NB + B - 1) / B, B, 0, stream>>>(btot, NB);
    kb_hist<<<gPart, B, 0, stream>>>(col, E, NB, btot);
    kb_scan<<<1, 1024, 0, stream>>>(btot, bstart, bcur, NB);
    kb_part<<<gPart, B, 0, stream>>>(row, col, E, NB, bcur, part);
    kb_csr<<<NB, B, 0, stream>>>(bstart, part, N, x, dis, off, srow, hsA, x0h);

    // GCN2 stack (layer L-1 fuses lin1)
    __half* bufs[2] = {hsA, hsB};
    const __half* hin = hsA;
    for (int l = 0; l < L; l++) {
        bool lastl = (l == L - 1);
        __half* hout = lastl ? nullptr : bufs[(l + 1) & 1];
        k_gcn2_fused<<<(N + 31) / 32, B, 0, stream>>>(
            srow, off, dis, hin, x0h, whT + (size_t)l * 4096,
            hout, lastl ? w1T : nullptr, t16s, N);
        hin = hout;
    }

    // tail
    k_prop16_lin2<<<(N + 3) / 4, B, 0, stream>>>(srow, off, dis, t16s, b1, w2, t1s, N);
    k_prop1<<<gN, B, 0, stream>>>(srow, off, dis, t1s, b2, out, N);
}